// Round 7
// baseline (663.012 us; speedup 1.0000x reference)
//
#include <hip/hip_runtime.h>

#define CF 128      // fine channels
#define HF 240      // fine H
#define WFIMG 320   // fine W
#define LCOARSE 4800
#define DC 256
#define WIN 5
#define PADW 2
#define NPOS 25
#define STRIDE 4    // setup_inputs() fixed
#define WCOARSE 80  // (320 + 2*2 - 5)/4 + 1

// ws layout (floats):
// [16384, 49152)        Wf4  [(k>>2)][o][k&3]    fused Wm2@w_down, k-vectorized
// [49152, 49280)        bfus [o]                 Wm2@b_down + b_merge
// [49280, 49280+2M*128) V    [g][o]              per-match coarse contribution

__global__ __launch_bounds__(256)
void prep_kernel(const float* __restrict__ w_down, const float* __restrict__ b_down,
                 const float* __restrict__ w_merge, const float* __restrict__ b_merge,
                 float* __restrict__ Wf4, float* __restrict__ bfus)
{
    int blk = blockIdx.x, tid = threadIdx.x;
    if (blk < 128) {
        // Wf[o][k] = sum_j w_merge[o][128+j] * w_down[j][k], stored k-vectorized
        int idx = blk * 256 + tid;   // 0..32767
        int klo = idx & 3;
        int o = (idx >> 2) & 127;
        int kg = idx >> 9;
        int k = kg * 4 + klo;
        float s = 0.f;
        for (int j = 0; j < 128; ++j)
            s += w_merge[o * 256 + 128 + j] * w_down[j * 256 + k];
        Wf4[idx] = s;
    } else {
        if (tid < 128) {
            float s = b_merge[tid];
            for (int j = 0; j < 128; ++j)
                s += w_merge[tid * 256 + 128 + j] * b_down[j];
            bfus[tid] = s;
        }
    }
}

#define NM 16  // matches per block in v_kernel

__global__ __launch_bounds__(256)
void v_kernel(const float* __restrict__ fc0, const float* __restrict__ fc1,
              const int* __restrict__ b_ids, const int* __restrict__ i_ids,
              const int* __restrict__ j_ids,
              const float* __restrict__ Wf4, const float* __restrict__ bfus,
              float* __restrict__ V, int M)
{
    __shared__ __align__(16) float smC[NM * 256];
    int tid = threadIdx.x;
    int m0 = blockIdx.x * NM;
    int total = 2 * M;

    for (int r = 0; r < NM; ++r) {
        int g = m0 + r;
        float v = 0.f;
        if (g < total) {
            int s = (g >= M) ? 1 : 0;
            int m = g - s * M;
            int b = b_ids[m];
            int id = s ? j_ids[m] : i_ids[m];
            const float* src = (s ? fc1 : fc0) + ((size_t)b * LCOARSE + id) * DC;
            v = src[tid];
        }
        smC[r * 256 + tid] = v;
    }
    __syncthreads();

    int o = tid & 127, h = tid >> 7;
    float acc[NM];
#pragma unroll
    for (int r = 0; r < NM; ++r) acc[r] = 0.f;

    // h=0 covers k in [0,128), h=1 covers k in [128,256): 32 float4 chunks each.
    // BUG FIXED (was kg<16: summed only half the coarse dims -> absmax 9.3125)
    for (int kg = 0; kg < 32; ++kg) {
        int k = h * 128 + kg * 4;
        float4 w = *(const float4*)&Wf4[(k >> 2) * 512 + o * 4];
#pragma unroll
        for (int r = 0; r < NM; ++r) {
            float4 c4 = *(const float4*)&smC[r * 256 + k];
            acc[r] += w.x * c4.x + w.y * c4.y + w.z * c4.z + w.w * c4.w;
        }
    }
    __syncthreads();
    float* red = smC;  // reuse: [NM][256]
#pragma unroll
    for (int r = 0; r < NM; ++r) red[r * 256 + h * 128 + o] = acc[r];
    __syncthreads();
    float bo = bfus[o];
    for (int r = h * (NM / 2); r < h * (NM / 2) + (NM / 2); ++r) {
        int g = m0 + r;
        if (g < total)
            V[(size_t)g * 128 + o] = red[r * 256 + o] + red[r * 256 + 128 + o] + bo;
    }
}

// acc.{x,y,z,w} = output rows o4+0..3 ; wrI = w_merge row (o4+I), k-chunk ; F = f[p][k-chunk]
#define DOT4(ACC, F)                                                 \
    ACC.x += wr0.x * F.x + wr0.y * F.y + wr0.z * F.z + wr0.w * F.w;  \
    ACC.y += wr1.x * F.x + wr1.y * F.y + wr1.z * F.z + wr1.w * F.w;  \
    ACC.z += wr2.x * F.x + wr2.y * F.y + wr2.z * F.z + wr2.w * F.w;  \
    ACC.w += wr3.x * F.x + wr3.y * F.y + wr3.z * F.z + wr3.w * F.w;

// Fine path: LDS = smF only (12.8KB). W1 read straight from global w_merge
// in native row-major layout — no ws, no transpose, no smW.
__global__ __launch_bounds__(256)
void fine_main(const float* __restrict__ ff0, const float* __restrict__ ff1,
               const int* __restrict__ b_ids, const int* __restrict__ i_ids,
               const int* __restrict__ j_ids,
               const float* __restrict__ w_merge, const float* __restrict__ V,
               float* __restrict__ out, int M)
{
    __shared__ __align__(16) float smF[NPOS * 128];  // [p][k], 12.8KB

    int tid = threadIdx.x;
    int gid = blockIdx.x;
    int s = (gid >= M) ? 1 : 0;
    int m = gid - s * M;
    int b = b_ids[m];
    int id = s ? j_ids[m] : i_ids[m];
    int rr = id / WCOARSE, cc = id - rr * WCOARSE;
    int row0 = rr * STRIDE - PADW, col0 = cc * STRIDE - PADW;
    const float* feat = s ? ff1 : ff0;

    // stage 5x5x128 window -> smF[p][ch], zero-padded at borders
    for (int seg = tid; seg < CF * WIN; seg += 256) {
        int ch = seg / WIN;
        int wr = seg - ch * WIN;
        int row = row0 + wr;
        bool rok = ((unsigned)row < (unsigned)HF);
        const float* src = feat + ((size_t)(b * CF + ch) * HF + row) * WFIMG + col0;
#pragma unroll
        for (int wc = 0; wc < WIN; ++wc) {
            int col = col0 + wc;
            float v = (rok && (unsigned)col < (unsigned)WFIMG) ? src[wc] : 0.f;
            smF[(wr * WIN + wc) * 128 + ch] = v;
        }
    }
    __syncthreads();

    int og = tid & 31, pg = tid >> 5;
    int o4 = og * 4;
    int pb = pg * 3;          // p bases 0,3,...,21 ; pg7 covers 21..24
    bool last = (pg == 7);
    const float4* smFv = (const float4*)smF;     // [p][32]
    const float4* w4   = (const float4*)w_merge; // row = 64 float4; k-chunks 0..31

    float4 acc0 = {0.f, 0.f, 0.f, 0.f}, acc1 = acc0, acc2 = acc0, acc3 = acc0;
    for (int kg = 0; kg < 32; ++kg) {
        float4 wr0 = w4[(size_t)(o4 + 0) * 64 + kg];
        float4 wr1 = w4[(size_t)(o4 + 1) * 64 + kg];
        float4 wr2 = w4[(size_t)(o4 + 2) * 64 + kg];
        float4 wr3 = w4[(size_t)(o4 + 3) * 64 + kg];
        float4 f;
        f = smFv[(pb + 0) * 32 + kg];
        DOT4(acc0, f)
        f = smFv[(pb + 1) * 32 + kg];
        DOT4(acc1, f)
        f = smFv[(pb + 2) * 32 + kg];
        DOT4(acc2, f)
        if (last) {
            f = smFv[(pb + 3) * 32 + kg];
            DOT4(acc3, f)
        }
    }

    float4 vv = *(const float4*)&V[(size_t)gid * 128 + o4];
    float* dst = out + (size_t)gid * (NPOS * 128);
    float4 r;
    r.x = acc0.x + vv.x; r.y = acc0.y + vv.y; r.z = acc0.z + vv.z; r.w = acc0.w + vv.w;
    *(float4*)&dst[(pb + 0) * 128 + o4] = r;
    r.x = acc1.x + vv.x; r.y = acc1.y + vv.y; r.z = acc1.z + vv.z; r.w = acc1.w + vv.w;
    *(float4*)&dst[(pb + 1) * 128 + o4] = r;
    r.x = acc2.x + vv.x; r.y = acc2.y + vv.y; r.z = acc2.z + vv.z; r.w = acc2.w + vv.w;
    *(float4*)&dst[(pb + 2) * 128 + o4] = r;
    if (last) {
        r.x = acc3.x + vv.x; r.y = acc3.y + vv.y; r.z = acc3.z + vv.z; r.w = acc3.w + vv.w;
        *(float4*)&dst[(pb + 3) * 128 + o4] = r;
    }
}

extern "C" void kernel_launch(void* const* d_in, const int* in_sizes, int n_in,
                              void* d_out, int out_size, void* d_ws, size_t ws_size,
                              hipStream_t stream) {
    const float* ff0     = (const float*)d_in[0];
    const float* ff1     = (const float*)d_in[1];
    const float* fc0     = (const float*)d_in[2];
    const float* fc1     = (const float*)d_in[3];
    const float* w_down  = (const float*)d_in[4];
    const float* b_down  = (const float*)d_in[5];
    const float* w_merge = (const float*)d_in[6];
    const float* b_merge = (const float*)d_in[7];
    const int* b_ids     = (const int*)d_in[8];
    const int* i_ids     = (const int*)d_in[9];
    const int* j_ids     = (const int*)d_in[10];
    int M = in_sizes[8];

    float* wsf  = (float*)d_ws;
    float* Wf4  = wsf + 16384;
    float* bfus = wsf + 49152;
    float* V    = wsf + 49280;
    float* out  = (float*)d_out;

    prep_kernel<<<129, 256, 0, stream>>>(w_down, b_down, w_merge, b_merge, Wf4, bfus);
    v_kernel<<<(2 * M + NM - 1) / NM, 256, 0, stream>>>(fc0, fc1, b_ids, i_ids, j_ids,
                                                        Wf4, bfus, V, M);
    fine_main<<<2 * M, 256, 0, stream>>>(ff0, ff1, b_ids, i_ids, j_ids,
                                         w_merge, V, out, M);
}

// Round 8
// 322.677 us; speedup vs baseline: 2.0547x; 2.0547x over previous
//
#include <hip/hip_runtime.h>

#define CF 128      // fine channels
#define HF 240      // fine H
#define WFIMG 320   // fine W
#define LCOARSE 4800
#define DC 256
#define WIN 5
#define PADW 2
#define NPOS 25
#define STRIDE 4    // setup_inputs() fixed
#define WCOARSE 80  // (320 + 2*2 - 5)/4 + 1

#define SMF_LD 132  // smF padded leading dim (fp32): row*132 -> 2-way bank alias only
#define SMW_LD 136  // smWb padded leading dim (bf16): row*136 -> 2-way bank alias only

typedef __attribute__((ext_vector_type(8))) short bf16x8;
typedef __attribute__((ext_vector_type(8))) unsigned short ushort8;
typedef __attribute__((ext_vector_type(4))) float f32x4;

__device__ __forceinline__ unsigned short f2bf(float f) {
    unsigned u = __float_as_uint(f);
    return (unsigned short)((u + 0x7FFFu + ((u >> 16) & 1u)) >> 16);  // RNE
}

// ws layout (floats):
// [16384, 49152)         Wf4  [(k>>2)][o][k&3]   fused Wm2@w_down, k-vectorized
// [49152, 49280)         bfus [o]                Wm2@b_down + b_merge
// [49280, 49280+2M*128)  V    [g][o]             per-match coarse contribution
// [817280, 817280+8192)  Wb   [o][k] bf16 (as 16384 ushort) = bf16(w_merge[o][k])

__global__ __launch_bounds__(256)
void prep_kernel(const float* __restrict__ w_down, const float* __restrict__ b_down,
                 const float* __restrict__ w_merge, const float* __restrict__ b_merge,
                 float* __restrict__ Wf4, float* __restrict__ bfus,
                 unsigned short* __restrict__ Wb)
{
    int blk = blockIdx.x, tid = threadIdx.x;
    if (blk < 128) {
        // Wf[o][k] = sum_j w_merge[o][128+j] * w_down[j][k], stored k-vectorized
        int idx = blk * 256 + tid;   // 0..32767
        int klo = idx & 3;
        int o = (idx >> 2) & 127;
        int kg = idx >> 9;
        int k = kg * 4 + klo;
        float s = 0.f;
        for (int j = 0; j < 128; ++j)
            s += w_merge[o * 256 + 128 + j] * w_down[j * 256 + k];
        Wf4[idx] = s;
    } else if (blk == 128) {
        if (tid < 128) {
            float s = b_merge[tid];
            for (int j = 0; j < 128; ++j)
                s += w_merge[tid * 256 + 128 + j] * b_down[j];
            bfus[tid] = s;
        }
    } else {
        // Wb[o][k] = bf16(w_merge[o][k]), o,k in [0,128)
        int idx = (blk - 129) * 256 + tid;   // 0..16383
        int o = idx >> 7, k = idx & 127;
        Wb[idx] = f2bf(w_merge[o * 256 + k]);
    }
}

#define NM 16  // matches per block in v_kernel

__global__ __launch_bounds__(256)
void v_kernel(const float* __restrict__ fc0, const float* __restrict__ fc1,
              const int* __restrict__ b_ids, const int* __restrict__ i_ids,
              const int* __restrict__ j_ids,
              const float* __restrict__ Wf4, const float* __restrict__ bfus,
              float* __restrict__ V, int M)
{
    __shared__ __align__(16) float smC[NM * 256];
    int tid = threadIdx.x;
    int m0 = blockIdx.x * NM;
    int total = 2 * M;

    for (int r = 0; r < NM; ++r) {
        int g = m0 + r;
        float v = 0.f;
        if (g < total) {
            int s = (g >= M) ? 1 : 0;
            int m = g - s * M;
            int b = b_ids[m];
            int id = s ? j_ids[m] : i_ids[m];
            const float* src = (s ? fc1 : fc0) + ((size_t)b * LCOARSE + id) * DC;
            v = src[tid];
        }
        smC[r * 256 + tid] = v;
    }
    __syncthreads();

    int o = tid & 127, h = tid >> 7;
    float acc[NM];
#pragma unroll
    for (int r = 0; r < NM; ++r) acc[r] = 0.f;

    // h=0 covers k in [0,128), h=1 covers k in [128,256): 32 float4 chunks each.
    for (int kg = 0; kg < 32; ++kg) {
        int k = h * 128 + kg * 4;
        float4 w = *(const float4*)&Wf4[(k >> 2) * 512 + o * 4];
#pragma unroll
        for (int r = 0; r < NM; ++r) {
            float4 c4 = *(const float4*)&smC[r * 256 + k];
            acc[r] += w.x * c4.x + w.y * c4.y + w.z * c4.z + w.w * c4.w;
        }
    }
    __syncthreads();
    float* red = smC;  // reuse: [NM][256]
#pragma unroll
    for (int r = 0; r < NM; ++r) red[r * 256 + h * 128 + o] = acc[r];
    __syncthreads();
    float bo = bfus[o];
    for (int r = h * (NM / 2); r < h * (NM / 2) + (NM / 2); ++r) {
        int g = m0 + r;
        if (g < total)
            V[(size_t)g * 128 + o] = red[r * 256 + o] + red[r * 256 + 128 + o] + bo;
    }
}

// MFMA fine path: W1 (bf16) staged ONCE per block in LDS, then ~8 matches/block.
// Per wave: 32x32 output tile (2 Mtiles x 2 Ntiles of 16x16), K=128 in 4 steps.
// LDS = smWb 34816B + smF 16896B = 51.7KB -> 3 blocks/CU.
__global__ __launch_bounds__(256)
void fine_mfma(const float* __restrict__ ff0, const float* __restrict__ ff1,
               const int* __restrict__ b_ids, const int* __restrict__ i_ids,
               const int* __restrict__ j_ids,
               const unsigned short* __restrict__ Wb, const float* __restrict__ V,
               float* __restrict__ out, int M)
{
    __shared__ unsigned short smWb[128 * SMW_LD];  // [o][k] bf16, padded
    __shared__ float smF[32 * SMF_LD];             // [p][k] fp32, padded; rows 25-31 zero

    int tid = threadIdx.x;
    int total = 2 * M;

    // stage Wb -> smWb once (coalesced 16B chunks; 2-way LDS write alias = free)
    for (int i = tid; i < 2048; i += 256) {
        ushort8 v = ((const ushort8*)Wb)[i];
        int o = i >> 4, c = i & 15;
        *(ushort8*)&smWb[o * SMW_LD + c * 8] = v;
    }
    // zero the A-pad rows (p = 25..31) once; staging never touches them
    for (int i = tid; i < 7 * SMF_LD; i += 256) smF[25 * SMF_LD + i] = 0.f;

    int wn = tid >> 6;        // wave id 0..3 -> output cols [wn*32, wn*32+32)
    int l  = tid & 63;
    int lo = l & 15, hi = l >> 4;
    int c0 = wn * 32 + lo, c1 = c0 + 16;

    for (int g = blockIdx.x; g < total; g += gridDim.x) {
        int s = (g >= M) ? 1 : 0;
        int m = g - s * M;
        int b = b_ids[m];
        int id = s ? j_ids[m] : i_ids[m];
        int rr = id / WCOARSE, cc = id - rr * WCOARSE;
        int row0 = rr * STRIDE - PADW, col0 = cc * STRIDE - PADW;
        const float* feat = s ? ff1 : ff0;

        __syncthreads();  // previous match's A-frag readers done before overwrite
        // stage 5x5x128 window -> smF[p][ch] (verified gather, stride SMF_LD)
        for (int seg = tid; seg < CF * WIN; seg += 256) {
            int ch = seg / WIN;
            int wr = seg - ch * WIN;
            int row = row0 + wr;
            bool rok = ((unsigned)row < (unsigned)HF);
            const float* src = feat + ((size_t)(b * CF + ch) * HF + row) * WFIMG + col0;
#pragma unroll
            for (int wc = 0; wc < WIN; ++wc) {
                int col = col0 + wc;
                float v = (rok && (unsigned)col < (unsigned)WFIMG) ? src[wc] : 0.f;
                smF[(wr * WIN + wc) * SMF_LD + ch] = v;
            }
        }
        __syncthreads();

        f32x4 acc00 = {0.f, 0.f, 0.f, 0.f}, acc01 = acc00, acc10 = acc00, acc11 = acc00;
#pragma unroll
        for (int ks = 0; ks < 4; ++ks) {
            int k = ks * 32 + hi * 8;
            // A-frags: rows lo and 16+lo, 8 consecutive k, fp32 -> bf16 RNE
            const float* pa0 = &smF[lo * SMF_LD + k];
            const float* pa1 = &smF[(16 + lo) * SMF_LD + k];
            float4 fa = *(const float4*)pa0, fb = *(const float4*)(pa0 + 4);
            float4 ga = *(const float4*)pa1, gb = *(const float4*)(pa1 + 4);
            bf16x8 a0, a1;
            a0[0] = (short)f2bf(fa.x); a0[1] = (short)f2bf(fa.y);
            a0[2] = (short)f2bf(fa.z); a0[3] = (short)f2bf(fa.w);
            a0[4] = (short)f2bf(fb.x); a0[5] = (short)f2bf(fb.y);
            a0[6] = (short)f2bf(fb.z); a0[7] = (short)f2bf(fb.w);
            a1[0] = (short)f2bf(ga.x); a1[1] = (short)f2bf(ga.y);
            a1[2] = (short)f2bf(ga.z); a1[3] = (short)f2bf(ga.w);
            a1[4] = (short)f2bf(gb.x); a1[5] = (short)f2bf(gb.y);
            a1[6] = (short)f2bf(gb.z); a1[7] = (short)f2bf(gb.w);
            // B-frags: B[k][col] = w_merge[col][k] -> smWb row c0/c1, 8 consecutive k
            bf16x8 b0 = *(const bf16x8*)&smWb[c0 * SMW_LD + k];
            bf16x8 b1 = *(const bf16x8*)&smWb[c1 * SMW_LD + k];
            acc00 = __builtin_amdgcn_mfma_f32_16x16x32_bf16(a0, b0, acc00, 0, 0, 0);
            acc01 = __builtin_amdgcn_mfma_f32_16x16x32_bf16(a0, b1, acc01, 0, 0, 0);
            acc10 = __builtin_amdgcn_mfma_f32_16x16x32_bf16(a1, b0, acc10, 0, 0, 0);
            acc11 = __builtin_amdgcn_mfma_f32_16x16x32_bf16(a1, b1, acc11, 0, 0, 0);
        }

        float v0 = V[(size_t)g * 128 + c0];
        float v1 = V[(size_t)g * 128 + c1];
        float* dst = out + (size_t)g * (NPOS * 128);
        // C/D layout (m89): col = lane&15, row = (lane>>4)*4 + j
#pragma unroll
        for (int j = 0; j < 4; ++j) {
            int r = hi * 4 + j;
            dst[r * 128 + c0] = acc00[j] + v0;
            dst[r * 128 + c1] = acc01[j] + v1;
            int r2 = 16 + r;
            if (r2 < NPOS) {
                dst[r2 * 128 + c0] = acc10[j] + v0;
                dst[r2 * 128 + c1] = acc11[j] + v1;
            }
        }
    }
}

extern "C" void kernel_launch(void* const* d_in, const int* in_sizes, int n_in,
                              void* d_out, int out_size, void* d_ws, size_t ws_size,
                              hipStream_t stream) {
    const float* ff0     = (const float*)d_in[0];
    const float* ff1     = (const float*)d_in[1];
    const float* fc0     = (const float*)d_in[2];
    const float* fc1     = (const float*)d_in[3];
    const float* w_down  = (const float*)d_in[4];
    const float* b_down  = (const float*)d_in[5];
    const float* w_merge = (const float*)d_in[6];
    const float* b_merge = (const float*)d_in[7];
    const int* b_ids     = (const int*)d_in[8];
    const int* i_ids     = (const int*)d_in[9];
    const int* j_ids     = (const int*)d_in[10];
    int M = in_sizes[8];

    float* wsf  = (float*)d_ws;
    float* Wf4  = wsf + 16384;
    float* bfus = wsf + 49152;
    float* V    = wsf + 49280;
    unsigned short* Wb = (unsigned short*)(wsf + 817280);
    float* out  = (float*)d_out;

    prep_kernel<<<193, 256, 0, stream>>>(w_down, b_down, w_merge, b_merge, Wf4, bfus, Wb);
    v_kernel<<<(2 * M + NM - 1) / NM, 256, 0, stream>>>(fc0, fc1, b_ids, i_ids, j_ids,
                                                        Wf4, bfus, V, M);
    fine_mfma<<<768, 256, 0, stream>>>(ff0, ff1, b_ids, i_ids, j_ids,
                                       Wb, V, out, M);
}